// Round 1
// baseline (89.124 us; speedup 1.0000x reference)
//
#include <hip/hip_runtime.h>

// ConvAttention: B=2, C=64, H=32, W=32, S=16, KS=5
// x flat: b*1048576 + c*16384 + p*16 + t    (p = h*32+w)
//
// Key exact simplification: softmax over t of (sQ[s] + sK[t] + b2) == softmax_t(sK[t]).
// Q, b2, and all t-independent constants cancel. out[b,c,p,s] = sum_t attn[t]*V[c,t],
// identical for all s.

__device__ __forceinline__ int reflect32(int i) {
    if (i < 0) i = -i;
    if (i >= 32) i = 62 - i;
    return i;
}

// K1: fused filter Akp[c'][k] (padded stride 28) = sum_c w2[64+c][k] * w1[64+c][c']
__global__ void k_fuse(const float* __restrict__ w1, const float* __restrict__ w2,
                       float* __restrict__ Akp) {
    int k  = blockIdx.x;   // 0..27 (25..27 = zero padding)
    int cp = threadIdx.x;  // 0..63
    float acc = 0.f;
    if (k < 25) {
        for (int c = 0; c < 64; ++c)
            acc += w2[(64 + c) * 25 + k] * w1[(64 + c) * 64 + cp];
    }
    Akp[cp * 28 + k] = acc;
}

// K2: u[k][idx] = sum_c Ak[c][k] * x[c][idx]   (M=25, K=64, N=32768 GEMM)
__global__ void __launch_bounds__(64) k_gemm(const float* __restrict__ x,
                                             const float* __restrict__ Akp,
                                             float* __restrict__ u) {
    __shared__ float4 aks[64 * 7];
    int tid = threadIdx.x;
    const float4* Ak4 = (const float4*)Akp;
    for (int j = tid; j < 448; j += 64) aks[j] = Ak4[j];
    __syncthreads();

    int idx = blockIdx.x * 64 + tid;       // (b,p,t) flattened: 0..32767
    int b   = idx >> 14;
    int pt  = idx & 16383;
    const float* xp = x + b * 1048576 + pt;

    float acc[28];
#pragma unroll
    for (int k = 0; k < 28; ++k) acc[k] = 0.f;

    for (int c = 0; c < 64; ++c) {
        float xv = xp[c * 16384];
#pragma unroll
        for (int q = 0; q < 7; ++q) {
            float4 a = aks[c * 7 + q];
            acc[q * 4 + 0] = fmaf(a.x, xv, acc[q * 4 + 0]);
            acc[q * 4 + 1] = fmaf(a.y, xv, acc[q * 4 + 1]);
            acc[q * 4 + 2] = fmaf(a.z, xv, acc[q * 4 + 2]);
            acc[q * 4 + 3] = fmaf(a.w, xv, acc[q * 4 + 3]);
        }
    }
#pragma unroll
    for (int k = 0; k < 25; ++k) u[k * 32768 + idx] = acc[k];
}

// K3: gather-shift sK from u, softmax over t, y = attn-mix of x, out = w1v@y + b1v
__global__ void __launch_bounds__(256) k_attn(const float* __restrict__ x,
                                              const float* __restrict__ u,
                                              const float* __restrict__ w1,
                                              const float* __restrict__ b1,
                                              float* __restrict__ out) {
    __shared__ float wT[64 * 65];   // transposed w1v, padded: wT[i*65+c] = w1[(128+c)*64+i]
    __shared__ float sk_s[4 * 16];
    __shared__ float y_s[4 * 64];

    int tid = threadIdx.x;
    int g0  = blockIdx.x * 4;       // 4 pixels per block
    int b   = g0 >> 10;
    int p0  = g0 & 1023;

    // stage transposed V-projection weights (conflict-free: bank = (i+c)%32)
    for (int j = tid; j < 4096; j += 256)
        wT[(j & 63) * 65 + (j >> 6)] = w1[8192 + j];

    // phase A: sK[pix][t] = sum_k u[k][reflect-shifted p][t]
    if (tid < 64) {
        int pix = tid >> 4, t = tid & 15;
        int p = p0 + pix;
        int h = p >> 5, w = p & 31;
        float acc = 0.f;
#pragma unroll
        for (int ky = 0; ky < 5; ++ky) {
            int rh = reflect32(h + ky - 2);
#pragma unroll
            for (int kx = 0; kx < 5; ++kx) {
                int rw = reflect32(w + kx - 2);
                int k  = ky * 5 + kx;
                acc += u[k * 32768 + b * 16384 + (rh * 32 + rw) * 16 + t];
            }
        }
        sk_s[pix * 16 + t] = acc;
    }
    __syncthreads();

    // phase C: per (pix, c'): softmax over t (broadcast LDS reads), y = sum_t a[t]*x[c'][t]
    int cc = tid & 63, pix = tid >> 6;
    int p  = p0 + pix;
    float sk[16];
#pragma unroll
    for (int t = 0; t < 16; ++t) sk[t] = sk_s[pix * 16 + t];
    float m = sk[0];
#pragma unroll
    for (int t = 1; t < 16; ++t) m = fmaxf(m, sk[t]);
    float e[16];
    float ssum = 0.f;
#pragma unroll
    for (int t = 0; t < 16; ++t) { e[t] = __expf(sk[t] - m); ssum += e[t]; }
    float inv = 1.0f / ssum;

    const float4* xp = (const float4*)(x + b * 1048576 + cc * 16384 + p * 16);
    float y = 0.f;
#pragma unroll
    for (int q = 0; q < 4; ++q) {
        float4 xv = xp[q];
        y += e[4 * q + 0] * xv.x + e[4 * q + 1] * xv.y +
             e[4 * q + 2] * xv.z + e[4 * q + 3] * xv.w;
    }
    y_s[pix * 64 + cc] = y * inv;
    __syncthreads();

    // phase D: out[c] = b1v[c] + sum_i wT[i][c] * y[i]; broadcast over all 16 s
    float acc = b1[128 + cc];
#pragma unroll 8
    for (int i = 0; i < 64; ++i)
        acc = fmaf(wT[i * 65 + cc], y_s[pix * 64 + i], acc);

    float4 v = make_float4(acc, acc, acc, acc);
    float4* op = (float4*)(out + (size_t)(b * 64 + cc) * 16384 + p * 16);
    op[0] = v; op[1] = v; op[2] = v; op[3] = v;
}

extern "C" void kernel_launch(void* const* d_in, const int* in_sizes, int n_in,
                              void* d_out, int out_size, void* d_ws, size_t ws_size,
                              hipStream_t stream) {
    const float* x  = (const float*)d_in[0];
    const float* w1 = (const float*)d_in[1];
    const float* b1 = (const float*)d_in[2];
    const float* w2 = (const float*)d_in[3];
    // b2 (d_in[4]) cancels in the softmax over t — unused.
    float* out = (float*)d_out;
    float* ws  = (float*)d_ws;

    float* Akp = ws;          // 64*28 floats (padded fused K-filter)
    float* u   = ws + 2048;   // 25*32768 floats (per-tap channel-contracted planes)

    k_fuse<<<28, 64, 0, stream>>>(w1, w2, Akp);
    k_gemm<<<512, 64, 0, stream>>>(x, Akp, u);
    k_attn<<<512, 256, 0, stream>>>(x, u, w1, b1, out);
}

// Round 2
// 88.490 us; speedup vs baseline: 1.0072x; 1.0072x over previous
//
#include <hip/hip_runtime.h>

// ConvAttention: B=2, C=64, H=32, W=32, S=16, KS=5
// x flat: b*1048576 + c*16384 + p*16 + t    (p = h*32+w)
//
// Exact simplification: softmax_t(sQ[s] + sK[t] + b2) == softmax_t(sK[t]).
// out[b,c,p,s] = sum_t attn[t] * V[c,t], identical for all s, where
// V = w1v @ x + b1v and sK = (fused 5x5 reflect-conv Ak) * x.
// We mix-then-project: y = sum_t attn[t]*x[:,t]; out = w1v@y + b1v  (64x less FMA).

__device__ __forceinline__ int reflect32(int i) {
    if (i < 0) i = -i;
    if (i >= 32) i = 62 - i;
    return i;
}

// K1: fused filter Akp[c'][k] (padded stride 28) = sum_c w2[64+c][k] * w1[64+c][c']
__global__ void k_fuse(const float* __restrict__ w1, const float* __restrict__ w2,
                       float* __restrict__ Akp) {
    int k  = blockIdx.x;   // 0..27 (25..27 zero pad)
    int cp = threadIdx.x;  // 0..63
    float acc = 0.f;
    if (k < 25) {
        for (int c = 0; c < 64; ++c)
            acc += w2[(64 + c) * 25 + k] * w1[(64 + c) * 64 + cp];
    }
    Akp[cp * 28 + k] = acc;
}

// K2: u[k][idx] = sum_c Ak[c][k] * x[c][idx]   (M=25, K=64, N=32768)
// 2 waves/block split taps 13/12; Ak read via uniform (readfirstlane) address ->
// scalar s_load from K$, no LDS, no per-lane Ak traffic.
__global__ void __launch_bounds__(128) k_gemm(const float* __restrict__ x,
                                              const float* __restrict__ Akp,
                                              float* __restrict__ u) {
    int tid  = threadIdx.x;
    int wave = tid >> 6;
    int l    = tid & 63;
    int idx  = blockIdx.x * 64 + l;        // (b,p,t) flattened
    int b    = idx >> 14;
    int pt   = idx & 16383;
    const float* xp = x + b * 1048576 + pt;

    // wave0: taps 0..12 (stores 0..12); wave1: taps 12..24 (stores 13..24)
    int k0 = __builtin_amdgcn_readfirstlane(wave ? 12 : 0);

    float acc[13];
#pragma unroll
    for (int k = 0; k < 13; ++k) acc[k] = 0.f;

#pragma unroll 4
    for (int c = 0; c < 64; ++c) {
        float xv = xp[c * 16384];
        const float* ak = Akp + c * 28 + k0;   // uniform -> s_load
#pragma unroll
        for (int k = 0; k < 13; ++k)
            acc[k] = fmaf(ak[k], xv, acc[k]);
    }

    int kstart = wave ? 1 : 0;
#pragma unroll
    for (int k = 0; k < 13; ++k)
        if (k >= kstart) u[(k0 + k) * 32768 + idx] = acc[k];
}

// K3: sk gather + softmax_t + y-mix (LDS-staged x tile) + w1v projection + store
__global__ void __launch_bounds__(256) k_attn(const float* __restrict__ x,
                                              const float* __restrict__ u,
                                              const float* __restrict__ w1,
                                              const float* __restrict__ b1,
                                              float* __restrict__ out) {
    __shared__ float wT[64 * 65];     // wT[i*65+cc] = w1v[cc][i]
    __shared__ float xs[4 * 1040];    // xs[pix*1040 + t*65 + cc]
    __shared__ float psk[4 * 64];     // psk[grp*64 + pix*16 + t]
    __shared__ float sk_s[64];        // sk_s[pix*16 + t]
    __shared__ float ysT[64 * 4];     // ysT[i*4 + pix]

    int tid = threadIdx.x;
    int g0  = blockIdx.x * 4;         // 4 pixels/block (same row: 4 | 32)
    int b   = g0 >> 10;
    int p0  = g0 & 1023;

    // --- stage x tile, coalesced: 4 lanes x 16B = 64B contiguous per cc ---
    {
        int cc = tid >> 2, sub = tid & 3;
        const float* xbase = x + b * 1048576 + cc * 16384 + p0 * 16 + sub * 4;
#pragma unroll
        for (int pix = 0; pix < 4; ++pix) {
            float4 v = *(const float4*)(xbase + pix * 16);
            float* dst = xs + pix * 1040 + (4 * sub) * 65 + cc;
            dst[0] = v.x; dst[65] = v.y; dst[130] = v.z; dst[195] = v.w;
        }
    }
    // --- stage transposed projection weights (stride-65: conflict-free) ---
    for (int e = tid; e < 4096; e += 256)
        wT[(e & 63) * 65 + (e >> 6)] = w1[8192 + e];   // e = c*64+i -> wT[i][c]

    // --- phase A: sk[pix][t] = sum_k u[k][reflected p][t], taps split 7/7/7/4 ---
    {
        int grp = tid >> 6;
        int pix = (tid >> 4) & 3;
        int t   = tid & 15;
        int p   = p0 + pix;
        int hh  = p >> 5, ww = p & 31;
        int kk0 = grp * 7;
        int nk  = (grp == 3) ? 4 : 7;
        const float* ub = u + b * 16384 + t;
        float acc = 0.f;
        for (int q = 0; q < nk; ++q) {
            int k  = kk0 + q;
            int ky = k / 5, kx = k - ky * 5;
            int rh = reflect32(hh + ky - 2);
            int rw = reflect32(ww + kx - 2);
            acc += ub[k * 32768 + (rh * 32 + rw) * 16];
        }
        psk[grp * 64 + pix * 16 + t] = acc;
    }
    __syncthreads();
    if (tid < 64)
        sk_s[tid] = psk[tid] + psk[64 + tid] + psk[128 + tid] + psk[192 + tid];
    __syncthreads();

    // --- phase C: softmax over t (wave-uniform broadcast), y-mix from LDS ---
    {
        int pix = tid >> 6, cc = tid & 63;
        float sk[16];
#pragma unroll
        for (int t = 0; t < 16; ++t) sk[t] = sk_s[pix * 16 + t];
        float m = sk[0];
#pragma unroll
        for (int t = 1; t < 16; ++t) m = fmaxf(m, sk[t]);
        float e[16], ssum = 0.f;
#pragma unroll
        for (int t = 0; t < 16; ++t) { e[t] = __expf(sk[t] - m); ssum += e[t]; }
        float inv = 1.0f / ssum;

        const float* xr = xs + pix * 1040 + cc;
        float y = 0.f;
#pragma unroll
        for (int t = 0; t < 16; ++t) y = fmaf(e[t], xr[t * 65], y);
        ysT[cc * 4 + pix] = y * inv;
    }
    __syncthreads();

    // --- phase D: o[pix][cc] = b1v[cc] + sum_i wT[i][cc]*y[pix][i]
    //     4-lane split over i (i = 4*ii+sub, conflict-free), shfl reduce ---
    {
        int cc = tid >> 2, sub = tid & 3;
        float o0 = 0.f, o1 = 0.f, o2 = 0.f, o3 = 0.f;
#pragma unroll
        for (int ii = 0; ii < 16; ++ii) {
            int i = ii * 4 + sub;
            float wv = wT[i * 65 + cc];
            float4 yv = *(const float4*)(ysT + i * 4);
            o0 = fmaf(wv, yv.x, o0);
            o1 = fmaf(wv, yv.y, o1);
            o2 = fmaf(wv, yv.z, o2);
            o3 = fmaf(wv, yv.w, o3);
        }
        o0 += __shfl_xor(o0, 1); o0 += __shfl_xor(o0, 2);
        o1 += __shfl_xor(o1, 1); o1 += __shfl_xor(o1, 2);
        o2 += __shfl_xor(o2, 1); o2 += __shfl_xor(o2, 2);
        o3 += __shfl_xor(o3, 1); o3 += __shfl_xor(o3, 2);
        float bb = b1[128 + cc];
        o0 += bb; o1 += bb; o2 += bb; o3 += bb;

        // store: broadcast over 16 s; 4 lanes x 16B = 64B contiguous per (cc,pix)
        float* ob = out + (size_t)(b * 64 + cc) * 16384 + p0 * 16 + sub * 4;
        *(float4*)(ob +  0) = make_float4(o0, o0, o0, o0);
        *(float4*)(ob + 16) = make_float4(o1, o1, o1, o1);
        *(float4*)(ob + 32) = make_float4(o2, o2, o2, o2);
        *(float4*)(ob + 48) = make_float4(o3, o3, o3, o3);
    }
}

extern "C" void kernel_launch(void* const* d_in, const int* in_sizes, int n_in,
                              void* d_out, int out_size, void* d_ws, size_t ws_size,
                              hipStream_t stream) {
    const float* x  = (const float*)d_in[0];
    const float* w1 = (const float*)d_in[1];
    const float* b1 = (const float*)d_in[2];
    const float* w2 = (const float*)d_in[3];
    // b2 (d_in[4]) cancels in the softmax over t — unused.
    float* out = (float*)d_out;
    float* ws  = (float*)d_ws;

    float* Akp = ws;          // 64*28 floats
    float* u   = ws + 2048;   // 25*32768 floats

    k_fuse<<<28, 64, 0, stream>>>(w1, w2, Akp);
    k_gemm<<<512, 128, 0, stream>>>(x, Akp, u);
    k_attn<<<512, 256, 0, stream>>>(x, u, w1, b1, out);
}